// Round 1
// baseline (862.717 us; speedup 1.0000x reference)
//
#include <hip/hip_runtime.h>

// Problem constants (from reference)
#define BB 2
#define HH 32
#define DD 128
#define D4 32          // DD/4 float4s per row
#define WW 1024
#define WLL 1020
#define NSINK 4
#define NC 7
#define STOT 8192      // NSINK + NC*WW + WLL

// Output: (2, B, H, STOT, D) f32 — every element is a gather from inputs.
// s in [0,4)        -> sink[b,h,s]
// s in [4,1024)     -> last[b,h,s-4]
// s in [1024,8192)  -> chunk j=(s-1024)>>10, cache index i=6-j, w=(s-1024)&1023
//    i in {4,5,6}           : cache[i][b,h,w]               (untouched)
//    i == 3, w <  1023      : cache[3][b,h,w]
//    i == 3, w == 1023      : replace ? cache[2][b,h,0] : cache[3][b,h,1023]
//    i in {0,1,2}, w < 1023 : cache[i][b,h,w+1]             (shift-left)
//    i in {1,2},  w == 1023 : cache[i-1][b,h,0]             (cascaded evict)
//    i == 0,      w == 1023 : key_states[b,h,0]
// replace = (0.99*cs[3,0,1023]+0.01*as[0,4099]) < (0.99*cs[2,0,0]+0.01*as[0,2052])

__global__ __launch_bounds__(256) void cascade_gather_kernel(
    const float4* __restrict__ key_states,    // (B,H,1,D)
    const float4* __restrict__ value_states,
    const float4* __restrict__ sink_keys,     // (B,H,4,D)
    const float4* __restrict__ sink_values,
    const float4* __restrict__ cache_keys,    // (7,B,H,W,D)
    const float4* __restrict__ cache_values,
    const float*  __restrict__ cache_scores,  // (7,B,W)
    const float4* __restrict__ last_keys,     // (B,H,WL,D)
    const float4* __restrict__ last_values,
    const float*  __restrict__ attn_scores,   // (B,STOT)
    float4* __restrict__ out)                 // (2,B,H,STOT,D)
{
    unsigned int idx = blockIdx.x * 256u + threadIdx.x;   // < 2*B*H*STOT*D4 = 33,554,432

    const int d4 = idx & 31;
    unsigned int t = idx >> 5;
    const int s = t & (STOT - 1);
    t >>= 13;
    const int h = t & (HH - 1);
    t >>= 5;
    const int b = t & 1;
    const int kv = (int)(t >> 1);

    const float4* __restrict__ sink  = kv ? sink_values  : sink_keys;
    const float4* __restrict__ last  = kv ? last_values  : last_keys;
    const float4* __restrict__ cache = kv ? cache_values : cache_keys;
    const float4* __restrict__ kvs   = kv ? value_states : key_states;

    float4 val;
    if (s < NSINK) {
        val = sink[((b * HH + h) * NSINK + s) * D4 + d4];
    } else if (s < NSINK + WLL) {
        val = last[((unsigned)(b * HH + h) * WLL + (s - NSINK)) * D4 + d4];
    } else {
        const int j = (s - 1024) >> 10;        // chunk 0..6
        const int w = (s - 1024) & 1023;
        const int i = 6 - j;                   // cache index

        int si = i, sw = w;
        bool from_new = false;

        if (i <= 2) {
            if (w < WW - 1) {
                sw = w + 1;                    // shift-left
            } else if (i == 0) {
                from_new = true;               // appended key/value state
            } else {
                si = i - 1; sw = 0;            // cascaded eviction
            }
        } else if (i == 3 && w == WW - 1) {
            // scalar replace predicate (batch 0 only, per reference)
            const float lhs = __fadd_rn(__fmul_rn(0.99f, cache_scores[(3 * BB + 0) * WW + (WW - 1)]),
                                        __fmul_rn(0.01f, attn_scores[NSINK + 3 * WW + (WW - 1)]));
            const float rhs = __fadd_rn(__fmul_rn(0.99f, cache_scores[(2 * BB + 0) * WW + 0]),
                                        __fmul_rn(0.01f, attn_scores[NSINK + 2 * WW + 0]));
            if (lhs < rhs) { si = 2; sw = 0; }
        }

        if (from_new) {
            val = kvs[(b * HH + h) * D4 + d4];
        } else {
            val = cache[(((unsigned)(si * BB + b) * HH + h) * WW + sw) * D4 + d4];
        }
    }

    out[idx] = val;
}

extern "C" void kernel_launch(void* const* d_in, const int* in_sizes, int n_in,
                              void* d_out, int out_size, void* d_ws, size_t ws_size,
                              hipStream_t stream) {
    const float4* key_states   = (const float4*)d_in[0];
    const float4* value_states = (const float4*)d_in[1];
    const float4* sink_keys    = (const float4*)d_in[2];
    const float4* sink_values  = (const float4*)d_in[3];
    const float4* cache_keys   = (const float4*)d_in[4];
    const float4* cache_values = (const float4*)d_in[5];
    const float*  cache_scores = (const float*)d_in[6];
    const float4* last_keys    = (const float4*)d_in[7];
    const float4* last_values  = (const float4*)d_in[8];
    // d_in[9] = last_scores (dead code — not used in output)
    const float*  attn_scores  = (const float*)d_in[10];

    float4* out = (float4*)d_out;

    const unsigned int total4 = 2u * BB * HH * STOT * D4;  // 33,554,432
    const unsigned int blocks = total4 / 256u;             // 131,072

    cascade_gather_kernel<<<blocks, 256, 0, stream>>>(
        key_states, value_states, sink_keys, sink_values,
        cache_keys, cache_values, cache_scores,
        last_keys, last_values, attn_scores, out);
}